// Round 2
// baseline (641.074 us; speedup 1.0000x reference)
//
#include <hip/hip_runtime.h>
#include <math.h>

#define N_NODES 50000
#define IN_CH 256
#define HID_CH 128
#define OUT_CH 1000
#define TEXT_DIM 768
#define N_EDGES 800000

// ---------------------------------------------------------------------------
// CSR build: count -> scan -> fill
// ---------------------------------------------------------------------------
__global__ void k_init_counts(int* __restrict__ pos, int n) {
    int i = blockIdx.x * blockDim.x + threadIdx.x;
    if (i < n) pos[i] = 0;
}

__global__ void k_count(const int* __restrict__ dst, int* __restrict__ pos, int e) {
    int i = blockIdx.x * blockDim.x + threadIdx.x;
    if (i < e) atomicAdd(&pos[dst[i]], 1);
}

// Single-block scan: 1024 threads, serial chunk + Hillis-Steele over partials.
__global__ __launch_bounds__(1024) void k_scan(const int* __restrict__ count,
                                               int* __restrict__ rowptr, int n) {
    __shared__ int part[1024];
    const int T = 1024;
    int t = threadIdx.x;
    int chunk = (n + T - 1) / T;
    int beg = t * chunk;
    int end = beg + chunk; if (end > n) end = n;
    int s = 0;
    for (int i = beg; i < end; ++i) s += count[i];
    part[t] = s;
    __syncthreads();
    for (int off = 1; off < T; off <<= 1) {
        int v = (t >= off) ? part[t - off] : 0;
        __syncthreads();
        part[t] += v;
        __syncthreads();
    }
    int run = part[t] - s;  // exclusive prefix for this chunk
    for (int i = beg; i < end; ++i) { rowptr[i] = run; run += count[i]; }
    if (t == T - 1) rowptr[n] = part[T - 1];
}

// dinv[v] = rsqrt(1 + in_degree), and pos[v] = rowptr[v] (fill cursor).
__global__ void k_dinv(const int* __restrict__ rowptr, float* __restrict__ dinv,
                       int* __restrict__ pos, int n) {
    int i = blockIdx.x * blockDim.x + threadIdx.x;
    if (i < n) {
        int c = rowptr[i + 1] - rowptr[i];
        dinv[i] = rsqrtf(1.0f + (float)c);
        pos[i] = rowptr[i];
    }
}

__global__ void k_fill(const int* __restrict__ src, const int* __restrict__ dst,
                       int* __restrict__ pos, const float* __restrict__ dinv,
                       int* __restrict__ csr_src, float* __restrict__ csr_norm, int e) {
    int i = blockIdx.x * blockDim.x + threadIdx.x;
    if (i < e) {
        int s = src[i], d = dst[i];
        int slot = atomicAdd(&pos[d], 1);
        csr_src[slot] = s;
        csr_norm[slot] = dinv[s] * dinv[d];
    }
}

// ---------------------------------------------------------------------------
// tvec[o] = bc[o] + sum_t text[t] * Wc[128+t][o]   (constant logit offset)
// ---------------------------------------------------------------------------
__global__ void k_tvec_init(const float* __restrict__ bc, float* __restrict__ tvec, int n) {
    int i = blockIdx.x * blockDim.x + threadIdx.x;
    if (i < n) tvec[i] = bc[i];
}

__global__ void k_tvec_acc(const float* __restrict__ text, const float* __restrict__ Wc,
                           float* __restrict__ tvec) {
    int o = blockIdx.x * blockDim.x + threadIdx.x;
    if (o >= OUT_CH) return;
    const int CH = TEXT_DIM / 16;  // 48
    int t0 = blockIdx.y * CH;
    float acc = 0.f;
    for (int t = t0; t < t0 + CH; ++t)
        acc += text[t] * Wc[(size_t)(HID_CH + t) * OUT_CH + o];
    atomicAdd(&tvec[o], acc);
}

// ---------------------------------------------------------------------------
// Tiled fp32 GEMM: C[M,N] = A[M,K] @ B[K,N] (+ vec[col] if ADD_VEC)
// BM=64, BN=64, BK=32, 256 threads, 4x4 per thread.
// ---------------------------------------------------------------------------
template <bool ADD_VEC>
__global__ __launch_bounds__(256)
void k_gemm(const float* __restrict__ A, const float* __restrict__ B,
            float* __restrict__ C, const float* __restrict__ vec,
            int M, int N, int K, int lda, int ldb, int ldc) {
    const int BK = 32;
    __shared__ float As[BK][64 + 4];  // A stored transposed: As[k][row]
    __shared__ float Bs[BK][64];

    int tid = threadIdx.x;
    int tx = tid & 15;        // col group
    int ty = tid >> 4;        // row group
    int rowBase = blockIdx.y * 64;
    int colBase = blockIdx.x * 64;

    int a_row = tid >> 3;         // 0..31
    int a_k = (tid & 7) * 4;      // 0,4,...,28
    int b_c = tid & 63;           // 0..63
    int b_k0 = tid >> 6;          // 0..3

    float acc[4][4] = {};

    for (int k0 = 0; k0 < K; k0 += BK) {
        // --- load A tile (rows a_row, a_row+32), float4 along K, transpose into LDS
#pragma unroll
        for (int rr = 0; rr < 2; ++rr) {
            int r = a_row + rr * 32;
            int grow = rowBase + r;
            float4 v = make_float4(0.f, 0.f, 0.f, 0.f);
            if (grow < M)
                v = *reinterpret_cast<const float4*>(&A[(size_t)grow * lda + k0 + a_k]);
            As[a_k + 0][r] = v.x;
            As[a_k + 1][r] = v.y;
            As[a_k + 2][r] = v.z;
            As[a_k + 3][r] = v.w;
        }
        // --- load B tile, coalesced scalar (guard N edge)
        int gc = colBase + b_c;
#pragma unroll
        for (int kk = 0; kk < 8; ++kk) {
            int k = kk * 4 + b_k0;
            float v = 0.f;
            if (gc < N) v = B[(size_t)(k0 + k) * ldb + gc];
            Bs[k][b_c] = v;
        }
        __syncthreads();
#pragma unroll
        for (int k = 0; k < BK; ++k) {
            float4 a = *reinterpret_cast<const float4*>(&As[k][ty * 4]);
            float4 b = *reinterpret_cast<const float4*>(&Bs[k][tx * 4]);
            float av[4] = {a.x, a.y, a.z, a.w};
            float bv[4] = {b.x, b.y, b.z, b.w};
#pragma unroll
            for (int i = 0; i < 4; ++i)
#pragma unroll
                for (int j = 0; j < 4; ++j) acc[i][j] += av[i] * bv[j];
        }
        __syncthreads();
    }

    // --- epilogue: float4 stores where possible
    int c0 = colBase + tx * 4;
    float4 vadd = make_float4(0.f, 0.f, 0.f, 0.f);
    if (ADD_VEC && c0 + 3 < N) vadd = *reinterpret_cast<const float4*>(&vec[c0]);
#pragma unroll
    for (int i = 0; i < 4; ++i) {
        int r = rowBase + ty * 4 + i;
        if (r >= M) continue;
        if (c0 + 3 < N) {
            float4 v = make_float4(acc[i][0] + vadd.x, acc[i][1] + vadd.y,
                                   acc[i][2] + vadd.z, acc[i][3] + vadd.w);
            *reinterpret_cast<float4*>(&C[(size_t)r * ldc + c0]) = v;
        } else {
#pragma unroll
            for (int j = 0; j < 4; ++j) {
                int c = c0 + j;
                if (c < N) {
                    float v = acc[i][j];
                    if (ADD_VEC) v += vec[c];
                    C[(size_t)r * ldc + c] = v;
                }
            }
        }
    }
}

// ---------------------------------------------------------------------------
// Gather aggregation: out[v] = bias + dinv[v]^2 * H[v] + sum_e norm_e * H[src_e]
// One block (128 threads) per node, one channel per thread.
// ---------------------------------------------------------------------------
template <bool RELU>
__global__ __launch_bounds__(128)
void k_aggregate(const float* __restrict__ H, const int* __restrict__ rowptr,
                 const int* __restrict__ csr_src, const float* __restrict__ csr_norm,
                 const float* __restrict__ dinv, const float* __restrict__ bias,
                 float* __restrict__ out) {
    int v = blockIdx.x;
    int c = threadIdx.x;
    float di = dinv[v];
    float acc = H[(size_t)v * HID_CH + c] * di * di + bias[c];
    int e0 = rowptr[v], e1 = rowptr[v + 1];
    for (int e = e0; e < e1; ++e) {
        int s = csr_src[e];
        float w = csr_norm[e];
        acc += H[(size_t)s * HID_CH + c] * w;
    }
    if (RELU) acc = fmaxf(acc, 0.f);
    out[(size_t)v * HID_CH + c] = acc;
}

// ---------------------------------------------------------------------------
extern "C" void kernel_launch(void* const* d_in, const int* in_sizes, int n_in,
                              void* d_out, int out_size, void* d_ws, size_t ws_size,
                              hipStream_t stream) {
    const float* x    = (const float*)d_in[0];
    const int*   ei   = (const int*)d_in[1];
    const float* text = (const float*)d_in[2];
    const float* W1   = (const float*)d_in[3];
    const float* b1   = (const float*)d_in[4];
    const float* W2   = (const float*)d_in[5];
    const float* b2   = (const float*)d_in[6];
    const float* Wc   = (const float*)d_in[7];
    const float* bc   = (const float*)d_in[8];
    float* out = (float*)d_out;

    const int* e_src = ei;
    const int* e_dst = ei + N_EDGES;

    // workspace carve-out (256B aligned)
    char* ws = (char*)d_ws;
    size_t off = 0;
    auto alloc = [&](size_t bytes) {
        size_t o = off;
        off += (bytes + 255) & ~(size_t)255;
        return o;
    };
    float* buf0     = (float*)(ws + alloc((size_t)N_NODES * HID_CH * 4));
    float* buf1     = (float*)(ws + alloc((size_t)N_NODES * HID_CH * 4));
    float* dinv     = (float*)(ws + alloc((size_t)N_NODES * 4));
    int*   rowptr   = (int*)  (ws + alloc((size_t)(N_NODES + 1) * 4));
    int*   pos      = (int*)  (ws + alloc((size_t)N_NODES * 4));
    int*   csr_src  = (int*)  (ws + alloc((size_t)N_EDGES * 4));
    float* csr_norm = (float*)(ws + alloc((size_t)N_EDGES * 4));
    float* tvec     = (float*)(ws + alloc((size_t)OUT_CH * 4));
    (void)ws_size; (void)in_sizes; (void)n_in; (void)out_size;

    // --- graph structure ---
    k_init_counts<<<(N_NODES + 255) / 256, 256, 0, stream>>>(pos, N_NODES);
    k_count<<<(N_EDGES + 255) / 256, 256, 0, stream>>>(e_dst, pos, N_EDGES);
    k_scan<<<1, 1024, 0, stream>>>(pos, rowptr, N_NODES);
    k_dinv<<<(N_NODES + 255) / 256, 256, 0, stream>>>(rowptr, dinv, pos, N_NODES);
    k_fill<<<(N_EDGES + 255) / 256, 256, 0, stream>>>(e_src, e_dst, pos, dinv,
                                                      csr_src, csr_norm, N_EDGES);

    // --- constant logit offset from text vector ---
    k_tvec_init<<<(OUT_CH + 255) / 256, 256, 0, stream>>>(bc, tvec, OUT_CH);
    {
        dim3 g((OUT_CH + 255) / 256, 16);
        k_tvec_acc<<<g, 256, 0, stream>>>(text, Wc, tvec);
    }

    // --- layer 1: GEMM + aggregate(+b1, ReLU) ---
    {
        dim3 g((HID_CH + 63) / 64, (N_NODES + 63) / 64);
        k_gemm<false><<<g, 256, 0, stream>>>(x, W1, buf0, nullptr,
                                             N_NODES, HID_CH, IN_CH, IN_CH, HID_CH, HID_CH);
    }
    k_aggregate<true><<<N_NODES, 128, 0, stream>>>(buf0, rowptr, csr_src, csr_norm,
                                                   dinv, b1, buf1);

    // --- layer 2: GEMM + aggregate(+b2) ---
    {
        dim3 g((HID_CH + 63) / 64, (N_NODES + 63) / 64);
        k_gemm<false><<<g, 256, 0, stream>>>(buf1, W2, buf0, nullptr,
                                             N_NODES, HID_CH, HID_CH, HID_CH, HID_CH, HID_CH);
    }
    k_aggregate<false><<<N_NODES, 128, 0, stream>>>(buf0, rowptr, csr_src, csr_norm,
                                                    dinv, b2, buf1);

    // --- classifier: out = buf1 @ Wc[:128] + tvec ---
    {
        dim3 g((OUT_CH + 63) / 64, (N_NODES + 63) / 64);
        k_gemm<true><<<g, 256, 0, stream>>>(buf1, Wc, out, tvec,
                                            N_NODES, OUT_CH, HID_CH, HID_CH, OUT_CH, OUT_CH);
    }
}

// Round 3
// 474.284 us; speedup vs baseline: 1.3517x; 1.3517x over previous
//
#include <hip/hip_runtime.h>
#include <math.h>

#define N_NODES 50000
#define IN_CH 256
#define HID_CH 128
#define OUT_CH 1000
#define TEXT_DIM 768
#define N_EDGES 800000

typedef __attribute__((ext_vector_type(8))) short bf16x8;
typedef __attribute__((ext_vector_type(4))) float f32x4;

union U16B { uint4 u; bf16x8 b; ushort s[8]; };

__device__ inline ushort f2bf(float f) {
    union { float f; unsigned u; } v; v.f = f;
    unsigned u = v.u;
    unsigned r = (u + 0x7FFFu + ((u >> 16) & 1u)) >> 16;  // RNE
    return (ushort)r;
}
__device__ inline float bf2f(unsigned s) {
    union { unsigned u; float f; } v; v.u = s << 16; return v.f;
}

// ---------------------------------------------------------------------------
// CSR build: count -> scan -> fill
// ---------------------------------------------------------------------------
__global__ void k_init_counts(int* __restrict__ pos, int n) {
    int i = blockIdx.x * blockDim.x + threadIdx.x;
    if (i < n) pos[i] = 0;
}

__global__ void k_count(const int* __restrict__ dst, int* __restrict__ pos, int e) {
    int i = blockIdx.x * blockDim.x + threadIdx.x;
    if (i < e) atomicAdd(&pos[dst[i]], 1);
}

__global__ __launch_bounds__(1024) void k_scan(const int* __restrict__ count,
                                               int* __restrict__ rowptr, int n) {
    __shared__ int part[1024];
    const int T = 1024;
    int t = threadIdx.x;
    int chunk = (n + T - 1) / T;
    int beg = t * chunk;
    int end = beg + chunk; if (end > n) end = n;
    int s = 0;
    for (int i = beg; i < end; ++i) s += count[i];
    part[t] = s;
    __syncthreads();
    for (int off = 1; off < T; off <<= 1) {
        int v = (t >= off) ? part[t - off] : 0;
        __syncthreads();
        part[t] += v;
        __syncthreads();
    }
    int run = part[t] - s;
    for (int i = beg; i < end; ++i) { rowptr[i] = run; run += count[i]; }
    if (t == T - 1) rowptr[n] = part[T - 1];
}

__global__ void k_dinv(const int* __restrict__ rowptr, float* __restrict__ dinv,
                       int* __restrict__ pos, int n) {
    int i = blockIdx.x * blockDim.x + threadIdx.x;
    if (i < n) {
        int c = rowptr[i + 1] - rowptr[i];
        dinv[i] = rsqrtf(1.0f + (float)c);
        pos[i] = rowptr[i];
    }
}

__global__ void k_fill(const int* __restrict__ src, const int* __restrict__ dst,
                       int* __restrict__ pos, const float* __restrict__ dinv,
                       int* __restrict__ csr_src, float* __restrict__ csr_norm, int e) {
    int i = blockIdx.x * blockDim.x + threadIdx.x;
    if (i < e) {
        int s = src[i], d = dst[i];
        int slot = atomicAdd(&pos[d], 1);
        csr_src[slot] = s;
        csr_norm[slot] = dinv[s] * dinv[d];
    }
}

// ---------------------------------------------------------------------------
// tvec[o] = bc[o] + sum_t text[t] * Wc[128+t][o]
// ---------------------------------------------------------------------------
__global__ void k_tvec_init(const float* __restrict__ bc, float* __restrict__ tvec, int n) {
    int i = blockIdx.x * blockDim.x + threadIdx.x;
    if (i < n) tvec[i] = bc[i];
}

__global__ void k_tvec_acc(const float* __restrict__ text, const float* __restrict__ Wc,
                           float* __restrict__ tvec) {
    int o = blockIdx.x * blockDim.x + threadIdx.x;
    if (o >= OUT_CH) return;
    const int CH = TEXT_DIM / 16;
    int t0 = blockIdx.y * CH;
    float acc = 0.f;
    for (int t = t0; t < t0 + CH; ++t)
        acc += text[t] * Wc[(size_t)(HID_CH + t) * OUT_CH + o];
    atomicAdd(&tvec[o], acc);
}

// ---------------------------------------------------------------------------
// Transpose + bf16 convert: in fp32 [Kdim][ld_in] -> out bf16 [Npad][Kdim]
// grid (Npad/64, Kdim/64), 256 threads. n >= Ndim rows are zero-filled.
// ---------------------------------------------------------------------------
__global__ __launch_bounds__(256)
void k_transpose(const float* __restrict__ in, int ld_in, int Ndim, int Kdim,
                 ushort* __restrict__ out) {
    __shared__ float t[64][65];
    int n0 = blockIdx.x * 64, k0 = blockIdx.y * 64;
    int c = threadIdx.x & 63, r0 = threadIdx.x >> 6;
    for (int r = r0; r < 64; r += 4) {
        int n = n0 + c, k = k0 + r;
        t[r][c] = (n < Ndim) ? in[(size_t)k * ld_in + n] : 0.f;
    }
    __syncthreads();
    for (int r = r0; r < 64; r += 4) {
        out[(size_t)(n0 + r) * Kdim + k0 + c] = f2bf(t[c][r]);
    }
}

// ---------------------------------------------------------------------------
// MFMA GEMM: C[M,N] = A[M,K] @ Bt[N,K]^T  (Bt is pre-transposed bf16 [Npad][K])
// Block: 256 thr (4 waves, 2x2), BM=64, N swept in 64-col chunks.
// A staged to LDS (bf16, XOR-swizzled), fragments hoisted to registers.
// CLS: fp32 out + tvec[col] added, masks on M/N edges. else: bf16 out, N=128.
// ---------------------------------------------------------------------------
template<int K, bool AF32, bool CLS>
__global__ __launch_bounds__(256)
void k_mfma_gemm(const void* __restrict__ Av, const uint4* __restrict__ Bt,
                 void* __restrict__ Cv, const float* __restrict__ tvec,
                 int M, int N) {
    constexpr int SLOTS = K / 8;              // 16B slots per row
    __shared__ uint4 ldsA[64 * SLOTS];
    __shared__ uint4 ldsB[64 * SLOTS];
    const int tid = threadIdx.x;
    const int lane = tid & 63;
    const int wid = tid >> 6;
    const int wm = wid >> 1, wn = wid & 1;    // 2x2 wave grid, each wave 32x32
    const int mbase = blockIdx.x * 64;

    // ---- stage A tile (convert fp32->bf16 if AF32), swizzled ----
    for (int i = tid; i < 64 * SLOTS; i += 256) {
        int row = i / SLOTS, slot = i % SLOTS;
        int grow = mbase + row;
        uint4 val = make_uint4(0u, 0u, 0u, 0u);
        if (grow < M) {
            if (AF32) {
                const float4* Af = (const float4*)Av;
                float4 f0 = Af[(size_t)grow * (K / 4) + slot * 2];
                float4 f1 = Af[(size_t)grow * (K / 4) + slot * 2 + 1];
                U16B o;
                o.s[0] = f2bf(f0.x); o.s[1] = f2bf(f0.y);
                o.s[2] = f2bf(f0.z); o.s[3] = f2bf(f0.w);
                o.s[4] = f2bf(f1.x); o.s[5] = f2bf(f1.y);
                o.s[6] = f2bf(f1.z); o.s[7] = f2bf(f1.w);
                val = o.u;
            } else {
                const uint4* Au = (const uint4*)Av;
                val = Au[(size_t)grow * SLOTS + slot];
            }
        }
        ldsA[row * SLOTS + (slot ^ (row & 7))] = val;
    }
    __syncthreads();

    // ---- hoist A fragments: rows wm*32 + mi*16 + (lane&15), all K ----
    bf16x8 afrag[2][K / 32];
#pragma unroll
    for (int mi = 0; mi < 2; ++mi) {
        int row = wm * 32 + mi * 16 + (lane & 15);
#pragma unroll
        for (int ks = 0; ks < K / 32; ++ks) {
            int slot = ks * 4 + (lane >> 4);
            U16B u; u.u = ldsA[row * SLOTS + (slot ^ (row & 7))];
            afrag[mi][ks] = u.b;
        }
    }

    const int nchunks = (N + 63) / 64;
    for (int ch = 0; ch < nchunks; ++ch) {
        int nbase = ch * 64;
        __syncthreads();   // protect ldsB from previous chunk's readers
        for (int i = tid; i < 64 * SLOTS; i += 256) {
            int row = i / SLOTS, slot = i % SLOTS;
            ldsB[row * SLOTS + (slot ^ (row & 7))] = Bt[(size_t)(nbase + row) * SLOTS + slot];
        }
        __syncthreads();

        f32x4 acc[2][2];
#pragma unroll
        for (int mi = 0; mi < 2; ++mi)
#pragma unroll
            for (int ni = 0; ni < 2; ++ni)
                acc[mi][ni] = f32x4{0.f, 0.f, 0.f, 0.f};

#pragma unroll
        for (int ks = 0; ks < K / 32; ++ks) {
            bf16x8 bfr[2];
#pragma unroll
            for (int ni = 0; ni < 2; ++ni) {
                int row = wn * 32 + ni * 16 + (lane & 15);
                int slot = ks * 4 + (lane >> 4);
                U16B u; u.u = ldsB[row * SLOTS + (slot ^ (row & 7))];
                bfr[ni] = u.b;
            }
#pragma unroll
            for (int mi = 0; mi < 2; ++mi)
#pragma unroll
                for (int ni = 0; ni < 2; ++ni)
                    acc[mi][ni] = __builtin_amdgcn_mfma_f32_16x16x32_bf16(
                        afrag[mi][ks], bfr[ni], acc[mi][ni], 0, 0, 0);
        }

        // ---- epilogue ----
#pragma unroll
        for (int ni = 0; ni < 2; ++ni) {
            int col = nbase + wn * 32 + ni * 16 + (lane & 15);
            float tv = 0.f;
            if (CLS) tv = (col < N) ? tvec[col] : 0.f;
#pragma unroll
            for (int mi = 0; mi < 2; ++mi) {
                int r0 = mbase + wm * 32 + mi * 16 + (lane >> 4) * 4;
#pragma unroll
                for (int j = 0; j < 4; ++j) {
                    int r = r0 + j;
                    if (CLS) {
                        if (r < M && col < N)
                            ((float*)Cv)[(size_t)r * N + col] = acc[mi][ni][j] + tv;
                    } else {
                        if (r < M)
                            ((ushort*)Cv)[(size_t)r * N + col] = f2bf(acc[mi][ni][j]);
                    }
                }
            }
        }
    }
}

// ---------------------------------------------------------------------------
// Aggregate (bf16 H): one wave per node, lane holds 2 channels (bf16x2 u32).
// out[v] = bias + dinv[v]^2 * H[v] + sum_e norm_e * H[src_e]   (+ReLU)
// ---------------------------------------------------------------------------
template<bool RELU>
__global__ __launch_bounds__(256)
void k_agg(const unsigned* __restrict__ Hu, const int* __restrict__ rowptr,
           const int* __restrict__ csr_src, const float* __restrict__ csr_norm,
           const float* __restrict__ dinv, const float* __restrict__ bias,
           unsigned* __restrict__ Ou) {
    int v = blockIdx.x * 4 + (threadIdx.x >> 6);
    if (v >= N_NODES) return;
    int lane = threadIdx.x & 63;
    float di = dinv[v];
    float sw = di * di;
    unsigned h = Hu[(size_t)v * 64 + lane];
    float a0 = bf2f(h & 0xffffu) * sw + bias[lane * 2];
    float a1 = bf2f(h >> 16) * sw + bias[lane * 2 + 1];
    int e0 = rowptr[v], e1 = rowptr[v + 1];
    for (int e = e0; e < e1; ++e) {
        int s = csr_src[e];
        float w = csr_norm[e];
        unsigned hv = Hu[(size_t)s * 64 + lane];
        a0 += bf2f(hv & 0xffffu) * w;
        a1 += bf2f(hv >> 16) * w;
    }
    if (RELU) { a0 = fmaxf(a0, 0.f); a1 = fmaxf(a1, 0.f); }
    Ou[(size_t)v * 64 + lane] = (unsigned)f2bf(a0) | ((unsigned)f2bf(a1) << 16);
}

// ---------------------------------------------------------------------------
extern "C" void kernel_launch(void* const* d_in, const int* in_sizes, int n_in,
                              void* d_out, int out_size, void* d_ws, size_t ws_size,
                              hipStream_t stream) {
    const float* x    = (const float*)d_in[0];
    const int*   ei   = (const int*)d_in[1];
    const float* text = (const float*)d_in[2];
    const float* W1   = (const float*)d_in[3];
    const float* b1   = (const float*)d_in[4];
    const float* W2   = (const float*)d_in[5];
    const float* b2   = (const float*)d_in[6];
    const float* Wc   = (const float*)d_in[7];
    const float* bc   = (const float*)d_in[8];
    float* out = (float*)d_out;

    const int* e_src = ei;
    const int* e_dst = ei + N_EDGES;

    char* ws = (char*)d_ws;
    size_t off = 0;
    auto alloc = [&](size_t bytes) {
        size_t o = off;
        off += (bytes + 255) & ~(size_t)255;
        return o;
    };
    ushort* h0      = (ushort*)(ws + alloc((size_t)N_NODES * HID_CH * 2));
    ushort* h1      = (ushort*)(ws + alloc((size_t)N_NODES * HID_CH * 2));
    float*  dinv    = (float*) (ws + alloc((size_t)N_NODES * 4));
    int*    rowptr  = (int*)   (ws + alloc((size_t)(N_NODES + 1) * 4));
    int*    pos     = (int*)   (ws + alloc((size_t)N_NODES * 4));
    int*    csr_src = (int*)   (ws + alloc((size_t)N_EDGES * 4));
    float*  csr_nrm = (float*) (ws + alloc((size_t)N_EDGES * 4));
    float*  tvec    = (float*) (ws + alloc((size_t)OUT_CH * 4));
    ushort* Wt1     = (ushort*)(ws + alloc((size_t)HID_CH * IN_CH * 2));   // [128][256]
    ushort* Wt2     = (ushort*)(ws + alloc((size_t)HID_CH * HID_CH * 2));  // [128][128]
    ushort* Wct     = (ushort*)(ws + alloc((size_t)1024 * HID_CH * 2));    // [1024][128], pad zeroed
    (void)ws_size; (void)in_sizes; (void)n_in; (void)out_size;

    // --- graph structure ---
    k_init_counts<<<(N_NODES + 255) / 256, 256, 0, stream>>>(pos, N_NODES);
    k_count<<<(N_EDGES + 255) / 256, 256, 0, stream>>>(e_dst, pos, N_EDGES);
    k_scan<<<1, 1024, 0, stream>>>(pos, rowptr, N_NODES);
    k_dinv<<<(N_NODES + 255) / 256, 256, 0, stream>>>(rowptr, dinv, pos, N_NODES);
    k_fill<<<(N_EDGES + 255) / 256, 256, 0, stream>>>(e_src, e_dst, pos, dinv,
                                                      csr_src, csr_nrm, N_EDGES);

    // --- weight transposes (fp32 -> bf16 [N][K]) ---
    {
        dim3 g1(HID_CH / 64, IN_CH / 64);     // (2,4): W1 [256][128] -> Wt1 [128][256]
        k_transpose<<<g1, 256, 0, stream>>>(W1, HID_CH, HID_CH, IN_CH, Wt1);
        dim3 g2(HID_CH / 64, HID_CH / 64);    // (2,2)
        k_transpose<<<g2, 256, 0, stream>>>(W2, HID_CH, HID_CH, HID_CH, Wt2);
        dim3 g3(1024 / 64, HID_CH / 64);      // (16,2): Wc[:128] -> Wct [1024][128]
        k_transpose<<<g3, 256, 0, stream>>>(Wc, OUT_CH, OUT_CH, HID_CH, Wct);
    }

    // --- constant logit offset ---
    k_tvec_init<<<(OUT_CH + 255) / 256, 256, 0, stream>>>(bc, tvec, OUT_CH);
    {
        dim3 g((OUT_CH + 255) / 256, 16);
        k_tvec_acc<<<g, 256, 0, stream>>>(text, Wc, tvec);
    }

    const int mtiles = (N_NODES + 63) / 64;   // 782

    // --- layer 1: x @ W1 (fp32 A, K=256) -> h0 bf16 ---
    k_mfma_gemm<IN_CH, true, false><<<mtiles, 256, 0, stream>>>(
        x, (const uint4*)Wt1, h0, nullptr, N_NODES, HID_CH);
    k_agg<true><<<(N_NODES + 3) / 4, 256, 0, stream>>>(
        (const unsigned*)h0, rowptr, csr_src, csr_nrm, dinv, b1, (unsigned*)h1);

    // --- layer 2: h1 @ W2 (bf16 A, K=128) -> h0 bf16 ---
    k_mfma_gemm<HID_CH, false, false><<<mtiles, 256, 0, stream>>>(
        h1, (const uint4*)Wt2, h0, nullptr, N_NODES, HID_CH);
    k_agg<false><<<(N_NODES + 3) / 4, 256, 0, stream>>>(
        (const unsigned*)h0, rowptr, csr_src, csr_nrm, dinv, b2, (unsigned*)h1);

    // --- classifier: h1 @ Wct^T + tvec -> out fp32 ---
    k_mfma_gemm<HID_CH, false, true><<<mtiles, 256, 0, stream>>>(
        h1, (const uint4*)Wct, out, tvec, N_NODES, OUT_CH);
}

// Round 4
// 453.096 us; speedup vs baseline: 1.4149x; 1.0468x over previous
//
#include <hip/hip_runtime.h>
#include <math.h>

#define N_NODES 50000
#define IN_CH 256
#define HID_CH 128
#define OUT_CH 1000
#define TEXT_DIM 768
#define N_EDGES 800000

typedef __attribute__((ext_vector_type(8))) short bf16x8;
typedef __attribute__((ext_vector_type(4))) float f32x4;

union U16B { uint4 u; bf16x8 b; ushort s[8]; };

__device__ inline ushort f2bf(float f) {
    union { float f; unsigned u; } v; v.f = f;
    unsigned u = v.u;
    unsigned r = (u + 0x7FFFu + ((u >> 16) & 1u)) >> 16;  // RNE
    return (ushort)r;
}
__device__ inline float bf2f(unsigned s) {
    union { unsigned u; float f; } v; v.u = s << 16; return v.f;
}

// ---------------------------------------------------------------------------
// CSR build
// ---------------------------------------------------------------------------
__global__ void k_count(const int* __restrict__ dst, int* __restrict__ pos, int e) {
    int i = blockIdx.x * blockDim.x + threadIdx.x;
    if (i < e) atomicAdd(&pos[dst[i]], 1);
}

// Single-block scan over counts; also emits dinv, resets pos to row start,
// and zeroes tvec (so k_tvec can atomically accumulate later).
__global__ __launch_bounds__(1024) void k_scan(int* __restrict__ count_pos,
                                               int* __restrict__ rowptr,
                                               float* __restrict__ dinv,
                                               float* __restrict__ tvec, int n) {
    __shared__ int part[1024];
    const int T = 1024;
    int t = threadIdx.x;
    for (int i = t; i < OUT_CH; i += T) tvec[i] = 0.f;
    int chunk = (n + T - 1) / T;
    int beg = t * chunk;
    int end = beg + chunk; if (end > n) end = n;
    int s = 0;
    for (int i = beg; i < end; ++i) s += count_pos[i];
    part[t] = s;
    __syncthreads();
    for (int off = 1; off < T; off <<= 1) {
        int v = (t >= off) ? part[t - off] : 0;
        __syncthreads();
        part[t] += v;
        __syncthreads();
    }
    int run = part[t] - s;
    for (int i = beg; i < end; ++i) {
        int c = count_pos[i];
        rowptr[i] = run;
        count_pos[i] = run;                 // pos cursor = row start
        dinv[i] = rsqrtf(1.0f + (float)c);
        run += c;
    }
    if (t == T - 1) rowptr[n] = part[T - 1];
}

__global__ void k_fill(const int* __restrict__ src, const int* __restrict__ dst,
                       int* __restrict__ pos, const float* __restrict__ dinv,
                       int* __restrict__ csr_src, float* __restrict__ csr_norm, int e) {
    int i = blockIdx.x * blockDim.x + threadIdx.x;
    if (i < e) {
        int s = src[i], d = dst[i];
        int slot = atomicAdd(&pos[d], 1);
        csr_src[slot] = s;
        csr_norm[slot] = dinv[s] * dinv[d];
    }
}

// ---------------------------------------------------------------------------
// tvec[o] += bc[o](chunk0) + sum_{t in chunk} text[t] * Wc[128+t][o]
// grid (4, TEXT_DIM/64), 256 threads. tvec pre-zeroed by k_scan.
// ---------------------------------------------------------------------------
__global__ void k_tvec(const float* __restrict__ text, const float* __restrict__ Wc,
                       const float* __restrict__ bc, float* __restrict__ tvec) {
    int o = blockIdx.x * 256 + threadIdx.x;
    if (o >= OUT_CH) return;
    int t0 = blockIdx.y * 64;
    float acc = (blockIdx.y == 0) ? bc[o] : 0.f;
#pragma unroll 4
    for (int t = t0; t < t0 + 64; ++t)
        acc += text[t] * Wc[(size_t)(HID_CH + t) * OUT_CH + o];
    atomicAdd(&tvec[o], acc);
}

// ---------------------------------------------------------------------------
// Transpose + bf16 convert: in fp32 [Kdim][ld_in] -> out bf16 [Npad][Kdim]
// ---------------------------------------------------------------------------
__global__ __launch_bounds__(256)
void k_transpose(const float* __restrict__ in, int ld_in, int Ndim, int Kdim,
                 ushort* __restrict__ out) {
    __shared__ float t[64][65];
    int n0 = blockIdx.x * 64, k0 = blockIdx.y * 64;
    int c = threadIdx.x & 63, r0 = threadIdx.x >> 6;
    for (int r = r0; r < 64; r += 4) {
        int n = n0 + c, k = k0 + r;
        t[r][c] = (n < Ndim) ? in[(size_t)k * ld_in + n] : 0.f;
    }
    __syncthreads();
    for (int r = r0; r < 64; r += 4) {
        out[(size_t)(n0 + r) * Kdim + k0 + c] = f2bf(t[c][r]);
    }
}

// ---------------------------------------------------------------------------
// MFMA GEMM: C[M,N] = A[M,K] @ Bt[N,K]^T  (Bt pre-transposed bf16 [Npad][K])
// Block: 256 thr (2x2 waves), BM=64. Each block handles NCH chunks of 64 cols
// starting at blockIdx.y*NCH. CLS: fp32 out + tvec, col/row masked.
// ---------------------------------------------------------------------------
template<int K, bool AF32, bool CLS, int NCH>
__global__ __launch_bounds__(256)
void k_mfma_gemm(const void* __restrict__ Av, const uint4* __restrict__ Bt,
                 void* __restrict__ Cv, const float* __restrict__ tvec,
                 int M, int N) {
    constexpr int SLOTS = K / 8;
    __shared__ uint4 ldsA[64 * SLOTS];
    __shared__ uint4 ldsB[64 * SLOTS];
    const int tid = threadIdx.x;
    const int lane = tid & 63;
    const int wid = tid >> 6;
    const int wm = wid >> 1, wn = wid & 1;
    const int mbase = blockIdx.x * 64;

    // ---- stage A tile (convert fp32->bf16 if AF32), XOR-swizzled ----
    for (int i = tid; i < 64 * SLOTS; i += 256) {
        int row = i / SLOTS, slot = i % SLOTS;
        int grow = mbase + row;
        uint4 val = make_uint4(0u, 0u, 0u, 0u);
        if (grow < M) {
            if (AF32) {
                const float4* Af = (const float4*)Av;
                float4 f0 = Af[(size_t)grow * (K / 4) + slot * 2];
                float4 f1 = Af[(size_t)grow * (K / 4) + slot * 2 + 1];
                U16B o;
                o.s[0] = f2bf(f0.x); o.s[1] = f2bf(f0.y);
                o.s[2] = f2bf(f0.z); o.s[3] = f2bf(f0.w);
                o.s[4] = f2bf(f1.x); o.s[5] = f2bf(f1.y);
                o.s[6] = f2bf(f1.z); o.s[7] = f2bf(f1.w);
                val = o.u;
            } else {
                const uint4* Au = (const uint4*)Av;
                val = Au[(size_t)grow * SLOTS + slot];
            }
        }
        ldsA[row * SLOTS + (slot ^ (row & 7))] = val;
    }
    __syncthreads();

    // ---- hoist A fragments ----
    bf16x8 afrag[2][K / 32];
#pragma unroll
    for (int mi = 0; mi < 2; ++mi) {
        int row = wm * 32 + mi * 16 + (lane & 15);
#pragma unroll
        for (int ks = 0; ks < K / 32; ++ks) {
            int slot = ks * 4 + (lane >> 4);
            U16B u; u.u = ldsA[row * SLOTS + (slot ^ (row & 7))];
            afrag[mi][ks] = u.b;
        }
    }

#pragma unroll
    for (int chi = 0; chi < NCH; ++chi) {
        int nbase = (blockIdx.y * NCH + chi) * 64;
        __syncthreads();
        for (int i = tid; i < 64 * SLOTS; i += 256) {
            int row = i / SLOTS, slot = i % SLOTS;
            ldsB[row * SLOTS + (slot ^ (row & 7))] = Bt[(size_t)(nbase + row) * SLOTS + slot];
        }
        __syncthreads();

        f32x4 acc[2][2];
#pragma unroll
        for (int mi = 0; mi < 2; ++mi)
#pragma unroll
            for (int ni = 0; ni < 2; ++ni)
                acc[mi][ni] = f32x4{0.f, 0.f, 0.f, 0.f};

#pragma unroll
        for (int ks = 0; ks < K / 32; ++ks) {
            bf16x8 bfr[2];
#pragma unroll
            for (int ni = 0; ni < 2; ++ni) {
                int row = wn * 32 + ni * 16 + (lane & 15);
                int slot = ks * 4 + (lane >> 4);
                U16B u; u.u = ldsB[row * SLOTS + (slot ^ (row & 7))];
                bfr[ni] = u.b;
            }
#pragma unroll
            for (int mi = 0; mi < 2; ++mi)
#pragma unroll
                for (int ni = 0; ni < 2; ++ni)
                    acc[mi][ni] = __builtin_amdgcn_mfma_f32_16x16x32_bf16(
                        afrag[mi][ks], bfr[ni], acc[mi][ni], 0, 0, 0);
        }

#pragma unroll
        for (int ni = 0; ni < 2; ++ni) {
            int col = nbase + wn * 32 + ni * 16 + (lane & 15);
            float tv = 0.f;
            if (CLS) tv = (col < N) ? tvec[col] : 0.f;
#pragma unroll
            for (int mi = 0; mi < 2; ++mi) {
                int r0 = mbase + wm * 32 + mi * 16 + (lane >> 4) * 4;
#pragma unroll
                for (int j = 0; j < 4; ++j) {
                    int r = r0 + j;
                    if (CLS) {
                        if (r < M && col < N)
                            ((float*)Cv)[(size_t)r * N + col] = acc[mi][ni][j] + tv;
                    } else {
                        if (r < M)
                            ((ushort*)Cv)[(size_t)r * N + col] = f2bf(acc[mi][ni][j]);
                    }
                }
            }
        }
    }
}

// ---------------------------------------------------------------------------
// Aggregate (bf16 H): one wave per node, lane = 2 channels (bf16x2 u32).
// Unrolled by 4: batches 4 independent gathers to hide L2/L3 latency.
// ---------------------------------------------------------------------------
template<bool RELU>
__global__ __launch_bounds__(256)
void k_agg(const unsigned* __restrict__ Hu, const int* __restrict__ rowptr,
           const int* __restrict__ csr_src, const float* __restrict__ csr_norm,
           const float* __restrict__ dinv, const float* __restrict__ bias,
           unsigned* __restrict__ Ou) {
    int v = blockIdx.x * 4 + (threadIdx.x >> 6);
    if (v >= N_NODES) return;
    int lane = threadIdx.x & 63;
    float di = dinv[v];
    float sw = di * di;
    unsigned h = Hu[(size_t)v * 64 + lane];
    float a0 = bf2f(h & 0xffffu) * sw + bias[lane * 2];
    float a1 = bf2f(h >> 16) * sw + bias[lane * 2 + 1];
    int e = rowptr[v], e1 = rowptr[v + 1];
    for (; e + 4 <= e1; e += 4) {
        int s0 = csr_src[e], s1 = csr_src[e + 1];
        int s2 = csr_src[e + 2], s3 = csr_src[e + 3];
        float w0 = csr_norm[e], w1 = csr_norm[e + 1];
        float w2 = csr_norm[e + 2], w3 = csr_norm[e + 3];
        unsigned q0 = Hu[(size_t)s0 * 64 + lane];
        unsigned q1 = Hu[(size_t)s1 * 64 + lane];
        unsigned q2 = Hu[(size_t)s2 * 64 + lane];
        unsigned q3 = Hu[(size_t)s3 * 64 + lane];
        a0 += bf2f(q0 & 0xffffu) * w0 + bf2f(q1 & 0xffffu) * w1
            + bf2f(q2 & 0xffffu) * w2 + bf2f(q3 & 0xffffu) * w3;
        a1 += bf2f(q0 >> 16) * w0 + bf2f(q1 >> 16) * w1
            + bf2f(q2 >> 16) * w2 + bf2f(q3 >> 16) * w3;
    }
    for (; e < e1; ++e) {
        int s = csr_src[e];
        float w = csr_norm[e];
        unsigned q = Hu[(size_t)s * 64 + lane];
        a0 += bf2f(q & 0xffffu) * w;
        a1 += bf2f(q >> 16) * w;
    }
    if (RELU) { a0 = fmaxf(a0, 0.f); a1 = fmaxf(a1, 0.f); }
    Ou[(size_t)v * 64 + lane] = (unsigned)f2bf(a0) | ((unsigned)f2bf(a1) << 16);
}

// ---------------------------------------------------------------------------
extern "C" void kernel_launch(void* const* d_in, const int* in_sizes, int n_in,
                              void* d_out, int out_size, void* d_ws, size_t ws_size,
                              hipStream_t stream) {
    const float* x    = (const float*)d_in[0];
    const int*   ei   = (const int*)d_in[1];
    const float* text = (const float*)d_in[2];
    const float* W1   = (const float*)d_in[3];
    const float* b1   = (const float*)d_in[4];
    const float* W2   = (const float*)d_in[5];
    const float* b2   = (const float*)d_in[6];
    const float* Wc   = (const float*)d_in[7];
    const float* bc   = (const float*)d_in[8];
    float* out = (float*)d_out;

    const int* e_src = ei;
    const int* e_dst = ei + N_EDGES;

    char* ws = (char*)d_ws;
    size_t off = 0;
    auto alloc = [&](size_t bytes) {
        size_t o = off;
        off += (bytes + 255) & ~(size_t)255;
        return o;
    };
    ushort* h0      = (ushort*)(ws + alloc((size_t)N_NODES * HID_CH * 2));
    ushort* h1      = (ushort*)(ws + alloc((size_t)N_NODES * HID_CH * 2));
    float*  dinv    = (float*) (ws + alloc((size_t)N_NODES * 4));
    int*    rowptr  = (int*)   (ws + alloc((size_t)(N_NODES + 1) * 4));
    int*    pos     = (int*)   (ws + alloc((size_t)N_NODES * 4));
    int*    csr_src = (int*)   (ws + alloc((size_t)N_EDGES * 4));
    float*  csr_nrm = (float*) (ws + alloc((size_t)N_EDGES * 4));
    float*  tvec    = (float*) (ws + alloc((size_t)OUT_CH * 4));
    ushort* Wt1     = (ushort*)(ws + alloc((size_t)HID_CH * IN_CH * 2));
    ushort* Wt2     = (ushort*)(ws + alloc((size_t)HID_CH * HID_CH * 2));
    ushort* Wct     = (ushort*)(ws + alloc((size_t)1024 * HID_CH * 2));
    (void)ws_size; (void)in_sizes; (void)n_in; (void)out_size;

    // --- graph structure ---
    hipMemsetAsync(pos, 0, (size_t)N_NODES * 4, stream);
    k_count<<<(N_EDGES + 255) / 256, 256, 0, stream>>>(e_dst, pos, N_EDGES);
    k_scan<<<1, 1024, 0, stream>>>(pos, rowptr, dinv, tvec, N_NODES);
    k_fill<<<(N_EDGES + 255) / 256, 256, 0, stream>>>(e_src, e_dst, pos, dinv,
                                                      csr_src, csr_nrm, N_EDGES);

    // --- constant logit offset (tvec zeroed in k_scan) ---
    {
        dim3 g(4, TEXT_DIM / 64);
        k_tvec<<<g, 256, 0, stream>>>(text, Wc, bc, tvec);
    }

    // --- weight transposes (fp32 -> bf16 [N][K]) ---
    {
        dim3 g1(HID_CH / 64, IN_CH / 64);
        k_transpose<<<g1, 256, 0, stream>>>(W1, HID_CH, HID_CH, IN_CH, Wt1);
        dim3 g2(HID_CH / 64, HID_CH / 64);
        k_transpose<<<g2, 256, 0, stream>>>(W2, HID_CH, HID_CH, HID_CH, Wt2);
        dim3 g3(1024 / 64, HID_CH / 64);
        k_transpose<<<g3, 256, 0, stream>>>(Wc, OUT_CH, OUT_CH, HID_CH, Wct);
    }

    const int mtiles = (N_NODES + 63) / 64;   // 782

    // --- layer 1: x @ W1 (fp32 A, K=256) -> h0 bf16 ---
    k_mfma_gemm<IN_CH, true, false, 2><<<dim3(mtiles, 1), 256, 0, stream>>>(
        x, (const uint4*)Wt1, h0, nullptr, N_NODES, HID_CH);
    k_agg<true><<<(N_NODES + 3) / 4, 256, 0, stream>>>(
        (const unsigned*)h0, rowptr, csr_src, csr_nrm, dinv, b1, (unsigned*)h1);

    // --- layer 2: h1 @ W2 (bf16 A, K=128) -> h0 bf16 ---
    k_mfma_gemm<HID_CH, false, false, 2><<<dim3(mtiles, 1), 256, 0, stream>>>(
        h1, (const uint4*)Wt2, h0, nullptr, N_NODES, HID_CH);
    k_agg<false><<<(N_NODES + 3) / 4, 256, 0, stream>>>(
        (const unsigned*)h0, rowptr, csr_src, csr_nrm, dinv, b2, (unsigned*)h1);

    // --- classifier: h1 @ Wct^T + tvec -> out fp32, N-chunks split on grid.y ---
    k_mfma_gemm<HID_CH, false, true, 4><<<dim3(mtiles, 4), 256, 0, stream>>>(
        h1, (const uint4*)Wct, out, tvec, N_NODES, OUT_CH);
}

// Round 5
// 296.540 us; speedup vs baseline: 2.1619x; 1.5279x over previous
//
#include <hip/hip_runtime.h>
#include <math.h>

#define N_NODES 50000
#define IN_CH 256
#define HID_CH 128
#define OUT_CH 1000
#define TEXT_DIM 768
#define N_EDGES 800000
#define NBLK_SCAN 196   // ceil(50000/256)

typedef __attribute__((ext_vector_type(8))) short bf16x8;
typedef __attribute__((ext_vector_type(4))) float f32x4;

union U16B { uint4 u; bf16x8 b; ushort s[8]; };

__device__ inline ushort f2bf(float f) {
    union { float f; unsigned u; } v; v.f = f;
    unsigned u = v.u;
    unsigned r = (u + 0x7FFFu + ((u >> 16) & 1u)) >> 16;  // RNE
    return (ushort)r;
}
__device__ inline float bf2f(unsigned s) {
    union { unsigned u; float f; } v; v.u = s << 16; return v.f;
}

// ---------------------------------------------------------------------------
// CSR build
// ---------------------------------------------------------------------------
__global__ void k_count(const int* __restrict__ dst, int* __restrict__ pos, int e) {
    int i = blockIdx.x * blockDim.x + threadIdx.x;
    if (i < e) atomicAdd(&pos[dst[i]], 1);
}

// Phase A: per-block (256 counts) partial sums.
__global__ __launch_bounds__(256)
void k_blocksum(const int* __restrict__ cnt, int* __restrict__ partial, int n) {
    int i = blockIdx.x * 256 + threadIdx.x;
    int c = (i < n) ? cnt[i] : 0;
#pragma unroll
    for (int d = 32; d > 0; d >>= 1) c += __shfl_down(c, d);
    __shared__ int ws[4];
    if ((threadIdx.x & 63) == 0) ws[threadIdx.x >> 6] = c;
    __syncthreads();
    if (threadIdx.x == 0) partial[blockIdx.x] = ws[0] + ws[1] + ws[2] + ws[3];
}

// Phase B: one block scans the partials (exclusive), zeroes tvec, rowptr[N]=E.
__global__ __launch_bounds__(256)
void k_scan_partials(int* __restrict__ partial, int nb,
                     float* __restrict__ tvec, int* __restrict__ rowptr) {
    int tid = threadIdx.x, lane = tid & 63, w = tid >> 6;
    for (int i = tid; i < OUT_CH; i += 256) tvec[i] = 0.f;
    if (tid == 0) rowptr[N_NODES] = N_EDGES;
    int c = (tid < nb) ? partial[tid] : 0;
    int x = c;
#pragma unroll
    for (int d = 1; d < 64; d <<= 1) { int t = __shfl_up(x, d); if (lane >= d) x += t; }
    __shared__ int ws[4];
    if (lane == 63) ws[w] = x;
    __syncthreads();
    if (tid == 0) { int r = 0; for (int k = 0; k < 4; ++k) { int t = ws[k]; ws[k] = r; r += t; } }
    __syncthreads();
    int excl = x - c + ws[w];
    if (tid < nb) partial[tid] = excl;
}

// Phase C: block-local scan + partial offset -> rowptr, pos cursor, dinv.
// NOTE: cnt and pos alias (each thread reads its element before writing it).
__global__ __launch_bounds__(256)
void k_scan_finish(int* __restrict__ cnt_pos, const int* __restrict__ ppref,
                   int* __restrict__ rowptr, float* __restrict__ dinv, int n) {
    int i = blockIdx.x * 256 + threadIdx.x;
    int lane = threadIdx.x & 63, w = threadIdx.x >> 6;
    int c = (i < n) ? cnt_pos[i] : 0;
    int x = c;
#pragma unroll
    for (int d = 1; d < 64; d <<= 1) { int t = __shfl_up(x, d); if (lane >= d) x += t; }
    __shared__ int ws[4];
    if (lane == 63) ws[w] = x;
    __syncthreads();
    if (threadIdx.x == 0) { int r = 0; for (int k = 0; k < 4; ++k) { int t = ws[k]; ws[k] = r; r += t; } }
    __syncthreads();
    int excl = x - c + ws[w] + ppref[blockIdx.x];
    if (i < n) {
        rowptr[i] = excl;
        cnt_pos[i] = excl;
        dinv[i] = rsqrtf(1.0f + (float)c);
    }
}

__global__ void k_fill(const int* __restrict__ src, const int* __restrict__ dst,
                       int* __restrict__ pos, const float* __restrict__ dinv,
                       int2* __restrict__ csr, int e) {
    int i = blockIdx.x * blockDim.x + threadIdx.x;
    if (i < e) {
        int s = src[i], d = dst[i];
        int slot = atomicAdd(&pos[d], 1);
        float nm = dinv[s] * dinv[d];
        csr[slot] = make_int2(s, __float_as_int(nm));
    }
}

// ---------------------------------------------------------------------------
// k_prep: fused weight transposes (fp32 [K][ld] -> bf16 [Npad][K]) + tvec.
// Blocks 0..7: Wt1, 8..11: Wt2, 12..43: Wct, 44..91: tvec chunks.
// ---------------------------------------------------------------------------
__device__ void transpose_tile(const float* __restrict__ in, int ld_in, int Ndim,
                               int Kdim, ushort* __restrict__ out, int bx, int by) {
    __shared__ float t[64][65];
    int n0 = bx * 64, k0 = by * 64;
    int c = threadIdx.x & 63, r0 = threadIdx.x >> 6;
    for (int r = r0; r < 64; r += 4) {
        int n = n0 + c, k = k0 + r;
        t[r][c] = (n < Ndim) ? in[(size_t)k * ld_in + n] : 0.f;
    }
    __syncthreads();
    for (int r = r0; r < 64; r += 4) {
        out[(size_t)(n0 + r) * Kdim + k0 + c] = f2bf(t[c][r]);
    }
}

__global__ __launch_bounds__(256)
void k_prep(const float* __restrict__ W1, const float* __restrict__ W2,
            const float* __restrict__ Wc, const float* __restrict__ bc,
            const float* __restrict__ text,
            ushort* __restrict__ Wt1, ushort* __restrict__ Wt2,
            ushort* __restrict__ Wct, float* __restrict__ tvec) {
    int b = blockIdx.x;
    if (b < 8) {                       // Wt1: [256][128] -> [128][256]
        transpose_tile(W1, HID_CH, HID_CH, IN_CH, Wt1, b % 2, b / 2);
    } else if (b < 12) {               // Wt2: [128][128] -> [128][128]
        int j = b - 8;
        transpose_tile(W2, HID_CH, HID_CH, HID_CH, Wt2, j % 2, j / 2);
    } else if (b < 44) {               // Wct: Wc[:128] [128][1000] -> [1024][128]
        int j = b - 12;
        transpose_tile(Wc, OUT_CH, OUT_CH, HID_CH, Wct, j % 16, j / 16);
    } else {                           // tvec: 4 o-chunks x 12 t-chunks
        int j = b - 44;
        int o = (j & 3) * 256 + threadIdx.x;
        int t0 = (j >> 2) * 64;
        if (o < OUT_CH) {
            float acc = (t0 == 0) ? bc[o] : 0.f;
#pragma unroll 4
            for (int t = t0; t < t0 + 64; ++t)
                acc += text[t] * Wc[(size_t)(HID_CH + t) * OUT_CH + o];
            atomicAdd(&tvec[o], acc);
        }
    }
}

// ---------------------------------------------------------------------------
// MFMA GEMM: C[M,N] = A[M,K] @ Bt[N,K]^T  (Bt pre-transposed bf16 [Npad][K])
// Block: 256 thr (2x2 waves), BM=64. NCH 64-col chunks at blockIdx.y*NCH.
// ---------------------------------------------------------------------------
template<int K, bool AF32, bool CLS, int NCH>
__global__ __launch_bounds__(256)
void k_mfma_gemm(const void* __restrict__ Av, const uint4* __restrict__ Bt,
                 void* __restrict__ Cv, const float* __restrict__ tvec,
                 int M, int N) {
    constexpr int SLOTS = K / 8;
    __shared__ uint4 ldsA[64 * SLOTS];
    __shared__ uint4 ldsB[64 * SLOTS];
    const int tid = threadIdx.x;
    const int lane = tid & 63;
    const int wid = tid >> 6;
    const int wm = wid >> 1, wn = wid & 1;
    const int mbase = blockIdx.x * 64;

    for (int i = tid; i < 64 * SLOTS; i += 256) {
        int row = i / SLOTS, slot = i % SLOTS;
        int grow = mbase + row;
        uint4 val = make_uint4(0u, 0u, 0u, 0u);
        if (grow < M) {
            if (AF32) {
                const float4* Af = (const float4*)Av;
                float4 f0 = Af[(size_t)grow * (K / 4) + slot * 2];
                float4 f1 = Af[(size_t)grow * (K / 4) + slot * 2 + 1];
                U16B o;
                o.s[0] = f2bf(f0.x); o.s[1] = f2bf(f0.y);
                o.s[2] = f2bf(f0.z); o.s[3] = f2bf(f0.w);
                o.s[4] = f2bf(f1.x); o.s[5] = f2bf(f1.y);
                o.s[6] = f2bf(f1.z); o.s[7] = f2bf(f1.w);
                val = o.u;
            } else {
                const uint4* Au = (const uint4*)Av;
                val = Au[(size_t)grow * SLOTS + slot];
            }
        }
        ldsA[row * SLOTS + (slot ^ (row & 7))] = val;
    }
    __syncthreads();

    bf16x8 afrag[2][K / 32];
#pragma unroll
    for (int mi = 0; mi < 2; ++mi) {
        int row = wm * 32 + mi * 16 + (lane & 15);
#pragma unroll
        for (int ks = 0; ks < K / 32; ++ks) {
            int slot = ks * 4 + (lane >> 4);
            U16B u; u.u = ldsA[row * SLOTS + (slot ^ (row & 7))];
            afrag[mi][ks] = u.b;
        }
    }

#pragma unroll
    for (int chi = 0; chi < NCH; ++chi) {
        int nbase = (blockIdx.y * NCH + chi) * 64;
        __syncthreads();
        for (int i = tid; i < 64 * SLOTS; i += 256) {
            int row = i / SLOTS, slot = i % SLOTS;
            ldsB[row * SLOTS + (slot ^ (row & 7))] = Bt[(size_t)(nbase + row) * SLOTS + slot];
        }
        __syncthreads();

        f32x4 acc[2][2];
#pragma unroll
        for (int mi = 0; mi < 2; ++mi)
#pragma unroll
            for (int ni = 0; ni < 2; ++ni)
                acc[mi][ni] = f32x4{0.f, 0.f, 0.f, 0.f};

#pragma unroll
        for (int ks = 0; ks < K / 32; ++ks) {
            bf16x8 bfr[2];
#pragma unroll
            for (int ni = 0; ni < 2; ++ni) {
                int row = wn * 32 + ni * 16 + (lane & 15);
                int slot = ks * 4 + (lane >> 4);
                U16B u; u.u = ldsB[row * SLOTS + (slot ^ (row & 7))];
                bfr[ni] = u.b;
            }
#pragma unroll
            for (int mi = 0; mi < 2; ++mi)
#pragma unroll
                for (int ni = 0; ni < 2; ++ni)
                    acc[mi][ni] = __builtin_amdgcn_mfma_f32_16x16x32_bf16(
                        afrag[mi][ks], bfr[ni], acc[mi][ni], 0, 0, 0);
        }

#pragma unroll
        for (int ni = 0; ni < 2; ++ni) {
            int col = nbase + wn * 32 + ni * 16 + (lane & 15);
            float tv = 0.f;
            if (CLS) tv = (col < N) ? tvec[col] : 0.f;
#pragma unroll
            for (int mi = 0; mi < 2; ++mi) {
                int r0 = mbase + wm * 32 + mi * 16 + (lane >> 4) * 4;
#pragma unroll
                for (int j = 0; j < 4; ++j) {
                    int r = r0 + j;
                    if (CLS) {
                        if (r < M && col < N)
                            ((float*)Cv)[(size_t)r * N + col] = acc[mi][ni][j] + tv;
                    } else {
                        if (r < M)
                            ((ushort*)Cv)[(size_t)r * N + col] = f2bf(acc[mi][ni][j]);
                    }
                }
            }
        }
    }
}

// ---------------------------------------------------------------------------
// Aggregate (bf16 H): one wave per node, lane = 2 channels (bf16x2 u32).
// csr entries are int2 {src, norm_bits}; unroll-4 batched gathers.
// ---------------------------------------------------------------------------
template<bool RELU>
__global__ __launch_bounds__(256)
void k_agg(const unsigned* __restrict__ Hu, const int* __restrict__ rowptr,
           const int2* __restrict__ csr, const float* __restrict__ dinv,
           const float* __restrict__ bias, unsigned* __restrict__ Ou) {
    int v = blockIdx.x * 4 + (threadIdx.x >> 6);
    if (v >= N_NODES) return;
    int lane = threadIdx.x & 63;
    float di = dinv[v];
    float sw = di * di;
    unsigned h = Hu[(size_t)v * 64 + lane];
    float a0 = bf2f(h & 0xffffu) * sw + bias[lane * 2];
    float a1 = bf2f(h >> 16) * sw + bias[lane * 2 + 1];
    int e = rowptr[v], e1 = rowptr[v + 1];
    for (; e + 4 <= e1; e += 4) {
        int2 c0 = csr[e],     c1 = csr[e + 1];
        int2 c2 = csr[e + 2], c3 = csr[e + 3];
        float w0 = __int_as_float(c0.y), w1 = __int_as_float(c1.y);
        float w2 = __int_as_float(c2.y), w3 = __int_as_float(c3.y);
        unsigned q0 = Hu[(size_t)c0.x * 64 + lane];
        unsigned q1 = Hu[(size_t)c1.x * 64 + lane];
        unsigned q2 = Hu[(size_t)c2.x * 64 + lane];
        unsigned q3 = Hu[(size_t)c3.x * 64 + lane];
        a0 += bf2f(q0 & 0xffffu) * w0 + bf2f(q1 & 0xffffu) * w1
            + bf2f(q2 & 0xffffu) * w2 + bf2f(q3 & 0xffffu) * w3;
        a1 += bf2f(q0 >> 16) * w0 + bf2f(q1 >> 16) * w1
            + bf2f(q2 >> 16) * w2 + bf2f(q3 >> 16) * w3;
    }
    for (; e < e1; ++e) {
        int2 ce = csr[e];
        float w = __int_as_float(ce.y);
        unsigned q = Hu[(size_t)ce.x * 64 + lane];
        a0 += bf2f(q & 0xffffu) * w;
        a1 += bf2f(q >> 16) * w;
    }
    if (RELU) { a0 = fmaxf(a0, 0.f); a1 = fmaxf(a1, 0.f); }
    Ou[(size_t)v * 64 + lane] = (unsigned)f2bf(a0) | ((unsigned)f2bf(a1) << 16);
}

// ---------------------------------------------------------------------------
extern "C" void kernel_launch(void* const* d_in, const int* in_sizes, int n_in,
                              void* d_out, int out_size, void* d_ws, size_t ws_size,
                              hipStream_t stream) {
    const float* x    = (const float*)d_in[0];
    const int*   ei   = (const int*)d_in[1];
    const float* text = (const float*)d_in[2];
    const float* W1   = (const float*)d_in[3];
    const float* b1   = (const float*)d_in[4];
    const float* W2   = (const float*)d_in[5];
    const float* b2   = (const float*)d_in[6];
    const float* Wc   = (const float*)d_in[7];
    const float* bc   = (const float*)d_in[8];
    float* out = (float*)d_out;

    const int* e_src = ei;
    const int* e_dst = ei + N_EDGES;

    char* ws = (char*)d_ws;
    size_t off = 0;
    auto alloc = [&](size_t bytes) {
        size_t o = off;
        off += (bytes + 255) & ~(size_t)255;
        return o;
    };
    ushort* h0      = (ushort*)(ws + alloc((size_t)N_NODES * HID_CH * 2));
    ushort* h1      = (ushort*)(ws + alloc((size_t)N_NODES * HID_CH * 2));
    float*  dinv    = (float*) (ws + alloc((size_t)N_NODES * 4));
    int*    rowptr  = (int*)   (ws + alloc((size_t)(N_NODES + 1) * 4));
    int*    pos     = (int*)   (ws + alloc((size_t)N_NODES * 4));
    int*    partial = (int*)   (ws + alloc((size_t)NBLK_SCAN * 4));
    int2*   csr     = (int2*)  (ws + alloc((size_t)N_EDGES * 8));
    float*  tvec    = (float*) (ws + alloc((size_t)OUT_CH * 4));
    ushort* Wt1     = (ushort*)(ws + alloc((size_t)HID_CH * IN_CH * 2));
    ushort* Wt2     = (ushort*)(ws + alloc((size_t)HID_CH * HID_CH * 2));
    ushort* Wct     = (ushort*)(ws + alloc((size_t)1024 * HID_CH * 2));
    (void)ws_size; (void)in_sizes; (void)n_in; (void)out_size;

    // --- graph structure ---
    hipMemsetAsync(pos, 0, (size_t)N_NODES * 4, stream);
    k_count<<<(N_EDGES + 255) / 256, 256, 0, stream>>>(e_dst, pos, N_EDGES);
    k_blocksum<<<NBLK_SCAN, 256, 0, stream>>>(pos, partial, N_NODES);
    k_scan_partials<<<1, 256, 0, stream>>>(partial, NBLK_SCAN, tvec, rowptr);
    k_scan_finish<<<NBLK_SCAN, 256, 0, stream>>>(pos, partial, rowptr, dinv, N_NODES);
    k_fill<<<(N_EDGES + 255) / 256, 256, 0, stream>>>(e_src, e_dst, pos, dinv,
                                                      csr, N_EDGES);

    // --- fused prep: weight transposes + tvec ---
    k_prep<<<92, 256, 0, stream>>>(W1, W2, Wc, bc, text, Wt1, Wt2, Wct, tvec);

    const int mtiles = (N_NODES + 63) / 64;   // 782

    // --- layer 1: x @ W1 (fp32 A, K=256) -> h0 bf16 ---
    k_mfma_gemm<IN_CH, true, false, 2><<<dim3(mtiles, 1), 256, 0, stream>>>(
        x, (const uint4*)Wt1, h0, nullptr, N_NODES, HID_CH);
    k_agg<true><<<(N_NODES + 3) / 4, 256, 0, stream>>>(
        (const unsigned*)h0, rowptr, csr, dinv, b1, (unsigned*)h1);

    // --- layer 2: h1 @ W2 (bf16 A, K=128) -> h0 bf16 ---
    k_mfma_gemm<HID_CH, false, false, 2><<<dim3(mtiles, 1), 256, 0, stream>>>(
        h1, (const uint4*)Wt2, h0, nullptr, N_NODES, HID_CH);
    k_agg<false><<<(N_NODES + 3) / 4, 256, 0, stream>>>(
        (const unsigned*)h0, rowptr, csr, dinv, b2, (unsigned*)h1);

    // --- classifier: h1 @ Wct^T + tvec -> out fp32, N-chunks split on grid.y ---
    k_mfma_gemm<HID_CH, false, true, 4><<<dim3(mtiles, 4), 256, 0, stream>>>(
        h1, (const uint4*)Wct, out, tvec, N_NODES, OUT_CH);
}